// Round 10
// baseline (84.374 us; speedup 1.0000x reference)
//
#include <hip/hip_runtime.h>
#include <math.h>

// GlobalMatch: subsample stride-4 -> per batch 4096 pts x 256 ch,
// all-pairs min distance (a vs b), score = 2*sigmoid(-sqrt(d2min)), 4x4 upsample.
//
// Batch-pipelined with co-resident role-split:
//   K1: gather b0,b1 (full machine)
//   K2: 512 blocks (2/CU): 256 gemm fine tiles (b0,b1) + 256 gather units (b2,b3)
//   K3: 256 gemm fine tiles (b2,b3)
//   K4: finalize (uniform 8-slot min)
// Kernel boundaries provide all cross-role ordering.

#define BATCH 4
#define CH    256
#define HH    256
#define WW    256
#define HW    (HH*WW)
#define NPTS  4096
#define EPSV  1e-6f

typedef _Float16 half8  __attribute__((ext_vector_type(8)));
typedef float    f32x4  __attribute__((ext_vector_type(4)));

typedef __attribute__((address_space(1))) const void global_cvoid;
typedef __attribute__((address_space(3))) void lds_void;

// ws layout (bytes)
#define AC_OFF   0u                           // fp16 chunks [b][kc(32)][n(4096)] * 16B = 8MB
#define BC_OFF   (8u << 20)                   // same, 8MB
#define A2_OFF   (16u << 20)                  // f32 [b][n]  a2 + 2eps*sa            (64KB)
#define B2_OFF   ((16u << 20) + (64u << 10))  // f32 [b][n]  b2 - 2eps*sb + C*eps^2  (64KB)
#define DP_OFF   ((16u << 20) + (128u << 10)) // f32 [b][n][8] per-mh min d2         (512KB)
#define WS_TOTAL ((16u << 20) + (640u << 10))

// ---------------------------------------------------------------- gather unit
// One (b, h, z) with 512 threads: w = t&63, c-group wv = t>>6.
// float4 loads (only .x used): same cache lines, 4x bytes/request for MLP.
__device__ __forceinline__ void gather_unit(const float* __restrict__ src,
                                            unsigned char* __restrict__ ws,
                                            int b, int h, int z, int t,
                                            float* red /* >=1024 floats */)
{
  const int w  = t & 63;
  const int wv = t >> 6;
  unsigned char* dst = ws + (z ? BC_OFF : AC_OFF);
  float* norms = (float*)(ws + (z ? B2_OFF : A2_OFF));
  const float epsSign = z ? -2.0f * EPSV : 2.0f * EPSV;
  const float addC    = z ? (float)CH * EPSV * EPSV : 0.0f;

  const float* rowbase = src + ((size_t)b * CH) * HW
                             + (size_t)(h * 4) * WW + (size_t)(w * 4);
  float ssum = 0.0f, ssq = 0.0f;
  #pragma unroll
  for (int i = 0; i < 4; ++i) {
    const int kc = wv * 4 + i;             // 16B chunk (8 channels)
    half8 hv;
    #pragma unroll
    for (int j = 0; j < 8; ++j) {
      const int c = kc * 8 + j;
      const float4 v4 = *reinterpret_cast<const float4*>(rowbase + (size_t)c * HW);
      const float v = v4.x;
      ssum += v;
      ssq  = fmaf(v, v, ssq);
      hv[j] = (_Float16)v;
    }
    *reinterpret_cast<half8*>(dst + ((size_t)((b * 32 + kc) * NPTS + h * 64 + w)) * 16) = hv;
  }

  red[(0 * 8 + wv) * 64 + w] = ssum;
  red[(1 * 8 + wv) * 64 + w] = ssq;
  __syncthreads();
  if (t < 64) {
    float sm = 0.f, sq = 0.f;
    #pragma unroll
    for (int g = 0; g < 8; ++g) {
      sm += red[(0 * 8 + g) * 64 + t];
      sq += red[(1 * 8 + g) * 64 + t];
    }
    norms[b * NPTS + h * 64 + t] = fmaf(epsSign, sm, sq) + addC;
  }
}

// ---------------------------------------------------------------- gemm tile (R2 structure)
// 512 thr / 8 waves; tile 256n x (64m * NSUB), K=256. A staged in two 128-row
// halves through smem -> af[2][8]/wave (wave owns 32n). B streamed as 64m
// tiles (32KB), double-buffered, counted vmcnt(4). XOR swizzle
// byte ^= ((row&7)<<4) on FULL offsets, BOTH global_load_lds source & ds_read.
// MFMA 16x16x32_f16 C/D: col=lane&15, row=(lane>>4)*4+reg.
__device__ __forceinline__ void stage_b_tile(const unsigned char* __restrict__ Bc,
                                             int b, int mbase,
                                             unsigned char* dst, int t) {
  const int wv = t >> 6;
  #pragma unroll
  for (int r = 0; r < 4; ++r) {            // 4 x 512thr x 16B = 32KB (NOT 8!)
    unsigned x  = (unsigned)(r * 512 + t) * 16;            // dest byte in 32KB tile
    unsigned lb = x ^ (((x >> 9) & 7) << 4);               // logical byte
    unsigned m_l = lb >> 9;                                // 0..63
    unsigned kcb = (lb & 511) >> 4;                        // 0..31
    const unsigned char* srcp =
        Bc + ((size_t)((b * 32 + kcb) * NPTS + mbase + m_l)) * 16;
    __builtin_amdgcn_global_load_lds((global_cvoid*)srcp,
                                     (lds_void*)(dst + (r * 8192 + wv * 1024)),
                                     16, 0, 0);
  }
}

template<int NSUB>
__device__ __forceinline__ void gemm_tile(const unsigned char* __restrict__ Ac,
                                          const unsigned char* __restrict__ Bc,
                                          const float* __restrict__ a2p,
                                          const float* __restrict__ b2pc,
                                          float* __restrict__ d2part,
                                          int b, int nbase, int mstart, int slot,
                                          int t, unsigned char* smem)
{
  const int l  = t & 63;
  const int wv = t >> 6;
  const int q  = (l >> 4) & 3;

  // ---- stage A (two 128-row halves through smem) and read fragments
  half8 af[2][8];
  #pragma unroll
  for (int hf = 0; hf < 2; ++hf) {
    #pragma unroll
    for (int r = 0; r < 8; ++r) {
      unsigned x  = (unsigned)(r * 512 + t) * 16;
      unsigned lb = x ^ (((x >> 9) & 7) << 4);
      unsigned n_l = lb >> 9;                              // 0..127
      unsigned kcb = (lb & 511) >> 4;
      const unsigned char* srcp =
          Ac + ((size_t)((b * 32 + kcb) * NPTS + nbase + hf * 128 + n_l)) * 16;
      __builtin_amdgcn_global_load_lds((global_cvoid*)srcp,
                                       (lds_void*)(smem + (r * 8192 + wv * 1024)),
                                       16, 0, 0);
    }
    asm volatile("s_waitcnt vmcnt(0)" ::: "memory");
    __builtin_amdgcn_s_barrier();
    if ((wv >> 2) == hf) {                 // waves 0-3 half0, 4-7 half1
      #pragma unroll
      for (int nf = 0; nf < 2; ++nf) {
        const unsigned rr = (wv & 3) * 32 + nf * 16 + (l & 15);
        const unsigned sw = (rr & 7) << 4;
        #pragma unroll
        for (int kk = 0; kk < 8; ++kk)
          af[nf][kk] = *reinterpret_cast<const half8*>(
              smem + ((rr * 512 + q * 16 + kk * 64) ^ sw));
      }
    }
    asm volatile("s_waitcnt lgkmcnt(0)" ::: "memory");
    __builtin_amdgcn_s_barrier();
  }

  float rmin[2][4];
  #pragma unroll
  for (int nf = 0; nf < 2; ++nf)
    #pragma unroll
    for (int r = 0; r < 4; ++r) rmin[nf][r] = 3.0e38f;

  // ---- main loop: NSUB B-tiles of 64 m, double-buffered, counted vmcnt
  stage_b_tile(Bc, b, mstart, smem, t);
  for (int mt = 0; mt < NSUB; ++mt) {
    unsigned char* cb = (mt & 1) ? smem + 32768 : smem;
    unsigned char* nb = (mt & 1) ? smem : smem + 32768;
    if (mt < NSUB - 1) {
      stage_b_tile(Bc, b, mstart + (mt + 1) * 64, nb, t);
      asm volatile("s_waitcnt vmcnt(4)" ::: "memory");     // tile mt landed
    } else {
      asm volatile("s_waitcnt vmcnt(0)" ::: "memory");
    }
    __builtin_amdgcn_s_barrier();

    f32x4 acc[2][4];
    #pragma unroll
    for (int nf = 0; nf < 2; ++nf)
      #pragma unroll
      for (int ms = 0; ms < 4; ++ms) acc[nf][ms] = (f32x4){0.f, 0.f, 0.f, 0.f};

    __builtin_amdgcn_s_setprio(1);
    #pragma unroll
    for (int kk = 0; kk < 8; ++kk) {
      half8 bf[4];
      #pragma unroll
      for (int ms = 0; ms < 4; ++ms) {
        const unsigned rrB = ms * 16 + (l & 15);
        bf[ms] = *reinterpret_cast<const half8*>(
            cb + ((rrB * 512 + q * 16 + kk * 64) ^ ((rrB & 7) << 4)));
      }
      #pragma unroll
      for (int ms = 0; ms < 4; ++ms) {
        acc[0][ms] = __builtin_amdgcn_mfma_f32_16x16x32_f16(af[0][kk], bf[ms], acc[0][ms], 0, 0, 0);
        acc[1][ms] = __builtin_amdgcn_mfma_f32_16x16x32_f16(af[1][kk], bf[ms], acc[1][ms], 0, 0, 0);
      }
    }
    __builtin_amdgcn_s_setprio(0);

    const int mbase = mstart + mt * 64;
    #pragma unroll
    for (int ms = 0; ms < 4; ++ms) {
      const float bp = b2pc[b * NPTS + mbase + ms * 16 + (l & 15)];
      #pragma unroll
      for (int r = 0; r < 4; ++r) {
        rmin[0][r] = fminf(rmin[0][r], fmaf(-2.0f, acc[0][ms][r], bp));
        rmin[1][r] = fminf(rmin[1][r], fmaf(-2.0f, acc[1][ms][r], bp));
      }
    }
    __builtin_amdgcn_s_barrier();          // cb consumed before restage
  }

  // ---- reduce over 16 col-lanes, add a2, write slot
  #pragma unroll
  for (int nf = 0; nf < 2; ++nf)
    #pragma unroll
    for (int r = 0; r < 4; ++r) {
      float v = rmin[nf][r];
      v = fminf(v, __shfl_xor(v, 1, 64));
      v = fminf(v, __shfl_xor(v, 2, 64));
      v = fminf(v, __shfl_xor(v, 4, 64));
      v = fminf(v, __shfl_xor(v, 8, 64));
      if ((l & 15) == 0) {
        const int n = nbase + wv * 32 + nf * 16 + q * 4 + r;
        d2part[(size_t)(b * NPTS + n) * 8 + slot] = v + a2p[b * NPTS + n];
      }
    }
}

// ---------------------------------------------------------------- kernels
__global__ __launch_bounds__(512) void gm_k1_gather01(
    const float* __restrict__ A, const float* __restrict__ B,
    unsigned char* __restrict__ ws)
{
  __shared__ float red[1024];
  const int bid = blockIdx.x;              // 256: h(64) x z(2) x b(2)
  const int h = bid & 63, z = (bid >> 6) & 1, b = bid >> 7;
  gather_unit(z ? B : A, ws, b, h, z, threadIdx.x, red);
}

// 512 blocks, 2/CU. Role by bit 3 of bid so every XCD (bid&7) gets an even
// gemm/gather mix (parity interleave would pin gemm to even XCDs only).
__global__ __launch_bounds__(512, 2) void gm_k2_gemm01_gather23(
    const float* __restrict__ A, const float* __restrict__ B,
    unsigned char* __restrict__ ws)
{
  __shared__ __align__(16) unsigned char smem[65536];
  const int bid = blockIdx.x;
  const int t   = threadIdx.x;
  const int idx = ((bid >> 4) << 3) | (bid & 7);           // 0..255 per role
  if (bid & 8) {                           // gather batches 2,3
    const int h = idx & 63, z = (idx >> 6) & 1, b = 2 + (idx >> 7);
    gather_unit(z ? B : A, ws, b, h, z, t, (float*)smem);
  } else {                                 // gemm fine tile, batches 0,1
    // blocks sharing (b,ns) have equal idx&15 -> same XCD -> A-strip in its L2
    const int ns = (idx & 7) | (((idx >> 3) & 1) << 3);
    const int mh = (idx >> 4) & 7;
    const int b  = idx >> 7;
    gemm_tile<8>(ws + AC_OFF, ws + BC_OFF,
                 (const float*)(ws + A2_OFF), (const float*)(ws + B2_OFF),
                 (float*)(ws + DP_OFF), b, ns * 256, mh * 512, mh, t, smem);
  }
}

__global__ __launch_bounds__(512, 2) void gm_k3_gemm23(
    unsigned char* __restrict__ ws)
{
  __shared__ __align__(16) unsigned char smem[65536];
  const int bid = blockIdx.x;              // 256 fine tiles for b2,b3
  const int ns = (bid & 7) | (((bid >> 3) & 1) << 3);
  const int mh = (bid >> 4) & 7;
  const int b  = 2 + (bid >> 7);
  gemm_tile<8>(ws + AC_OFF, ws + BC_OFF,
               (const float*)(ws + A2_OFF), (const float*)(ws + B2_OFF),
               (float*)(ws + DP_OFF), b, ns * 256, mh * 512, mh,
               threadIdx.x, smem);
}

__global__ __launch_bounds__(256) void gm_finalize(
    const float* __restrict__ d2part, float* __restrict__ out)
{
  const int id = blockIdx.x * 256 + threadIdx.x;      // b*4096 + n
  const f32x4 u  = *reinterpret_cast<const f32x4*>(d2part + (size_t)id * 8);
  const f32x4 w4 = *reinterpret_cast<const f32x4*>(d2part + (size_t)id * 8 + 4);
  const float d2 = fminf(fminf(fminf(u[0], u[1]), fminf(u[2], u[3])),
                         fminf(fminf(w4[0], w4[1]), fminf(w4[2], w4[3])));
  const float l2 = sqrtf(fmaxf(d2, 0.0f));
  const float s  = 2.0f / (1.0f + expf(l2));          // 2*sigmoid(-l2)
  const int b = id >> 12;
  const int n = id & 4095;
  const int h = n >> 6, w = n & 63;
  float4 v = make_float4(s, s, s, s);
  float* obase = out + ((size_t)(b * 256 + h * 4)) * 256 + w * 4;
  #pragma unroll
  for (int i = 0; i < 4; ++i)
    *reinterpret_cast<float4*>(obase + (size_t)i * 256) = v;
}

__global__ void gm_sentinel(float* out) { out[0] = 1.0e6f; }

extern "C" void kernel_launch(void* const* d_in, const int* in_sizes, int n_in,
                              void* d_out, int out_size, void* d_ws, size_t ws_size,
                              hipStream_t stream) {
  const float* a = (const float*)d_in[0];
  const float* b = (const float*)d_in[1];
  float* out = (float*)d_out;
  unsigned char* ws = (unsigned char*)d_ws;

  if (ws_size < (size_t)WS_TOTAL) {
    gm_sentinel<<<1, 1, 0, stream>>>(out);
    return;
  }

  gm_k1_gather01<<<256, 512, 0, stream>>>(a, b, ws);
  gm_k2_gemm01_gather23<<<512, 512, 0, stream>>>(a, b, ws);
  gm_k3_gemm23<<<256, 512, 0, stream>>>(ws);
  gm_finalize<<<64, 256, 0, stream>>>((const float*)(ws + DP_OFF), out);
}